// Round 4
// baseline (4402.154 us; speedup 1.0000x reference)
//
#include <hip/hip_runtime.h>
#include <math.h>

#define B 64
#define S 512
#define DIN 768
#define H 64
#define G4 256   // 4*H gates per direction
#define NG 512   // 2 directions * 4H
#define DM 128   // bidirectional output width

__device__ __forceinline__ float sigm(float x) {
    return 1.0f / (1.0f + __expf(-x));
}
__device__ __forceinline__ float tanh_fast(float x) {
    // tanh(x) = 1 - 2/(exp(2x)+1); exact at +-inf, ~1e-7 rel err
    return 1.0f - 2.0f / (__expf(2.0f * x) + 1.0f);
}

// Raw workgroup barrier that drains ONLY LDS (lgkmcnt), leaving global
// prefetch loads in flight. __syncthreads() would s_waitcnt vmcnt(0) and
// serialize every step on the freshest HBM load (~900 cy).
__device__ __forceinline__ void lds_barrier() {
    __builtin_amdgcn_sched_barrier(0);
    asm volatile("s_waitcnt lgkmcnt(0)" ::: "memory");
    __builtin_amdgcn_s_barrier();
    __builtin_amdgcn_sched_barrier(0);
}

// ---------------------------------------------------------------------------
// Pooling: word_ids are sorted per row -> run-length accumulate, no atomics.
// ---------------------------------------------------------------------------
__global__ void pool_kernel(const float* __restrict__ emb,
                            const int* __restrict__ ids,
                            float* __restrict__ merged) {
    int b = blockIdx.x;
    int d = blockIdx.y * 128 + threadIdx.x;
    __shared__ int ids_s[S];
    for (int i = threadIdx.x; i < S; i += blockDim.x) ids_s[i] = ids[b * S + i];
    __syncthreads();
    const float* eb = emb + (size_t)b * S * DIN + d;
    float* mb = merged + (size_t)b * S * DIN + d;
    float acc = 0.f;
    for (int s = 0; s < S; ++s) {
        acc += eb[(size_t)s * DIN];
        int id = ids_s[s];
        bool flush = (s == S - 1) || (ids_s[s + 1] != id);
        if (flush) {
            mb[(size_t)id * DIN] = acc;
            acc = 0.f;
        }
    }
}

// ---------------------------------------------------------------------------
// Mask: one 64-lane wave per (b,word) row; mask = (sum over 768 != 0)
// ---------------------------------------------------------------------------
__global__ void mask_kernel(const float* __restrict__ merged,
                            float* __restrict__ mask) {
    int row = blockIdx.x * 4 + (threadIdx.x >> 6);
    int lane = threadIdx.x & 63;
    const float* r = merged + (size_t)row * DIN;
    float s = 0.f;
    #pragma unroll
    for (int i = 0; i < DIN / 64; ++i) s += r[lane + i * 64];
    #pragma unroll
    for (int off = 32; off > 0; off >>= 1) s += __shfl_down(s, off);
    if (lane == 0) mask[row] = (s != 0.f) ? 1.0f : 0.0f;
}

// ---------------------------------------------------------------------------
// GEMM: C[m][n] = sum_k A[m][k] * Wt[n][k] + bias[n]
// ---------------------------------------------------------------------------
#define OUTER4(a, w)                                                       \
    acc[0][0] = fmaf(a.x, w.x, acc[0][0]);                                 \
    acc[0][1] = fmaf(a.x, w.y, acc[0][1]);                                 \
    acc[0][2] = fmaf(a.x, w.z, acc[0][2]);                                 \
    acc[0][3] = fmaf(a.x, w.w, acc[0][3]);                                 \
    acc[1][0] = fmaf(a.y, w.x, acc[1][0]);                                 \
    acc[1][1] = fmaf(a.y, w.y, acc[1][1]);                                 \
    acc[1][2] = fmaf(a.y, w.z, acc[1][2]);                                 \
    acc[1][3] = fmaf(a.y, w.w, acc[1][3]);                                 \
    acc[2][0] = fmaf(a.z, w.x, acc[2][0]);                                 \
    acc[2][1] = fmaf(a.z, w.y, acc[2][1]);                                 \
    acc[2][2] = fmaf(a.z, w.z, acc[2][2]);                                 \
    acc[2][3] = fmaf(a.z, w.w, acc[2][3]);                                 \
    acc[3][0] = fmaf(a.w, w.x, acc[3][0]);                                 \
    acc[3][1] = fmaf(a.w, w.y, acc[3][1]);                                 \
    acc[3][2] = fmaf(a.w, w.z, acc[3][2]);                                 \
    acc[3][3] = fmaf(a.w, w.w, acc[3][3]);

__global__ __launch_bounds__(256, 2) void gemm_nt_bias(
    const float* __restrict__ A, int K,
    const float* __restrict__ Wt, const float* __restrict__ bias,
    float* __restrict__ C) {
    __shared__ __align__(16) float As[16][68];
    __shared__ __align__(16) float Bs[16][68];
    int tid = threadIdx.x;
    int m0 = blockIdx.x * 64;
    int n0 = blockIdx.y * 64;
    int lr = tid >> 2;          // 0..63 tile row
    int lk = (tid & 3) << 2;    // k offset (float4)
    int tx = tid & 15, ty = tid >> 4;
    float acc[4][4] = {};
    const float* Ap = A + (size_t)(m0 + lr) * K + lk;
    const float* Wp = Wt + (size_t)(n0 + lr) * K + lk;

    float4 av = *(const float4*)(Ap);
    float4 wv = *(const float4*)(Wp);
    for (int k0 = 0; k0 < K; k0 += 16) {
        As[lk + 0][lr] = av.x; As[lk + 1][lr] = av.y;
        As[lk + 2][lr] = av.z; As[lk + 3][lr] = av.w;
        Bs[lk + 0][lr] = wv.x; Bs[lk + 1][lr] = wv.y;
        Bs[lk + 2][lr] = wv.z; Bs[lk + 3][lr] = wv.w;
        __syncthreads();
        float4 av2 = av, wv2 = wv;
        if (k0 + 16 < K) {
            av2 = *(const float4*)(Ap + k0 + 16);
            wv2 = *(const float4*)(Wp + k0 + 16);
        }
        #pragma unroll
        for (int k = 0; k < 16; ++k) {
            float4 a = *(const float4*)&As[k][ty << 2];
            float4 w = *(const float4*)&Bs[k][tx << 2];
            OUTER4(a, w);
        }
        __syncthreads();
        av = av2; wv = wv2;
    }
    float4 bv = *(const float4*)&bias[n0 + (tx << 2)];
    #pragma unroll
    for (int i = 0; i < 4; ++i) {
        float4 r;
        r.x = acc[i][0] + bv.x;
        r.y = acc[i][1] + bv.y;
        r.z = acc[i][2] + bv.z;
        r.w = acc[i][3] + bv.w;
        *(float4*)&C[(size_t)(m0 + (ty << 2) + i) * NG + n0 + (tx << 2)] = r;
    }
}

// ---------------------------------------------------------------------------
// Recurrence: 4 waves per (batch, direction) chain, K-SPLIT, raw LDS-only
// barrier. Wave w, lane j holds all 4 gates of hidden unit j over k in
// [16w,16w+16): 64 weight VGPRs/lane. Partials through double-buffered LDS;
// ONE lgkm-only barrier per step; activations recomputed redundantly in all
// waves so h stays replicated (bitwise identical) and needs no broadcast.
// ---------------------------------------------------------------------------
__global__ __launch_bounds__(256, 1) void lstm_rec(
    const float* __restrict__ pre,   // [B*S][512]
    const float* __restrict__ Whh,   // [512][64] (dir*256+g rows)
    const float* __restrict__ xin,   // [B*S][128] or nullptr
    float* __restrict__ xout,        // [B*S][128]
    int residual) {
    int b = blockIdx.x >> 1;
    int dir = blockIdx.x & 1;
    int t = threadIdx.x;
    int w = t >> 6;     // wave id 0..3 -> k range [16w, 16w+16)
    int j = t & 63;     // hidden unit

    // weights: wgtG[kk] = W_hh[dir*256 + G*64 + j][16w + kk]
    float wgt0[16], wgt1[16], wgt2[16], wgt3[16];
    {
        const float* base = Whh + (size_t)(dir * G4 + j) * H + (w << 4);
        #pragma unroll
        for (int kk = 0; kk < 16; kk += 4) {
            float4 v;
            v = *(const float4*)(base + (size_t)0 * 64 * H + kk);
            wgt0[kk] = v.x; wgt0[kk+1] = v.y; wgt0[kk+2] = v.z; wgt0[kk+3] = v.w;
            v = *(const float4*)(base + (size_t)1 * 64 * H + kk);
            wgt1[kk] = v.x; wgt1[kk+1] = v.y; wgt1[kk+2] = v.z; wgt1[kk+3] = v.w;
            v = *(const float4*)(base + (size_t)2 * 64 * H + kk);
            wgt2[kk] = v.x; wgt2[kk+1] = v.y; wgt2[kk+2] = v.z; wgt2[kk+3] = v.w;
            v = *(const float4*)(base + (size_t)3 * 64 * H + kk);
            wgt3[kk] = v.x; wgt3[kk+1] = v.y; wgt3[kk+2] = v.z; wgt3[kk+3] = v.w;
        }
    }

    // pre stream: wave w, lane j reads pre[s][dir*256 + w*64 + j]
    const float* preb = pre + (size_t)b * S * NG + dir * G4 + (w << 6) + j;
    const float* xinb = xin + (size_t)b * S * DM + dir * H + j;   // wave0 only
    float* xoutb = xout + (size_t)b * S * DM + dir * H + j;       // wave0 only

    float pbuf[4], rb[4] = {0.f, 0.f, 0.f, 0.f};
    #pragma unroll
    for (int i = 0; i < 4; ++i) {
        int s = dir ? (S - 1 - i) : i;
        pbuf[i] = preb[(size_t)s * NG];
        if (residual && w == 0) rb[i] = xinb[(size_t)s * DM];
    }

    __shared__ __align__(16) float part[2][4][64][4];

    float h = 0.f, c = 0.f;
    #pragma unroll 4
    for (int step = 0; step < S; ++step) {
        int s = dir ? (S - 1 - step) : step;
        int q = step & 3;
        int pp = step & 1;
        float p = pbuf[q];
        float rv = rb[q];
        int sn = step + 4;
        if (sn < S) {
            int s2 = dir ? (S - 1 - sn) : sn;
            pbuf[q] = preb[(size_t)s2 * NG];
            if (residual && w == 0) rb[q] = xinb[(size_t)s2 * DM];
        }

        float a0 = (w == 0) ? p : 0.f;
        float a1 = (w == 1) ? p : 0.f;
        float a2 = (w == 2) ? p : 0.f;
        float a3 = (w == 3) ? p : 0.f;
        #pragma unroll
        for (int kk = 0; kk < 16; ++kk) {
            float hk = __shfl(h, (w << 4) | kk);
            a0 = fmaf(hk, wgt0[kk], a0);
            a1 = fmaf(hk, wgt1[kk], a1);
            a2 = fmaf(hk, wgt2[kk], a2);
            a3 = fmaf(hk, wgt3[kk], a3);
        }
        *(float4*)&part[pp][w][j][0] = make_float4(a0, a1, a2, a3);
        lds_barrier();
        float4 v0 = *(const float4*)&part[pp][0][j][0];
        float4 v1 = *(const float4*)&part[pp][1][j][0];
        float4 v2 = *(const float4*)&part[pp][2][j][0];
        float4 v3 = *(const float4*)&part[pp][3][j][0];
        float gi = (v0.x + v1.x) + (v2.x + v3.x);
        float gf = (v0.y + v1.y) + (v2.y + v3.y);
        float gg = (v0.z + v1.z) + (v2.z + v3.z);
        float go = (v0.w + v1.w) + (v2.w + v3.w);
        c = sigm(gf) * c + sigm(gi) * tanh_fast(gg);
        h = sigm(go) * tanh_fast(c);
        if (w == 0) xoutb[(size_t)s * DM] = h + rv;
    }
}

// ---------------------------------------------------------------------------
// Assemble: out0[b,s,0:128] = x, out0[b,s,128] = sn_word_len[b,s]
// ---------------------------------------------------------------------------
__global__ void assemble_kernel(const float* __restrict__ x,
                                const float* __restrict__ wl,
                                float* __restrict__ out0) {
    int idx = blockIdx.x * blockDim.x + threadIdx.x;
    if (idx >= B * S * 129) return;
    int c = idx % 129;
    int bs = idx / 129;
    out0[idx] = (c < 128) ? x[(size_t)bs * DM + c] : wl[bs];
}

extern "C" void kernel_launch(void* const* d_in, const int* in_sizes, int n_in,
                              void* d_out, int out_size, void* d_ws, size_t ws_size,
                              hipStream_t stream) {
    const float* emb  = (const float*)d_in[0];
    const float* wl   = (const float*)d_in[1];
    const float* Wih1 = (const float*)d_in[2];  // [512][768]
    const float* Whh1 = (const float*)d_in[3];  // [512][64]
    const float* b1   = (const float*)d_in[4];  // [512]
    const float* Wih  = (const float*)d_in[5];  // [7][512][128]
    const float* Whh  = (const float*)d_in[6];  // [7][512][64]
    const float* bb   = (const float*)d_in[7];  // [7][512]
    const int*   ids  = (const int*)d_in[8];

    float* out0 = (float*)d_out;
    float* mask_out = out0 + (size_t)B * S * 129;

    float* merged = (float*)d_ws;                       // 25165824 f
    float* pre    = merged + (size_t)B * S * DIN;       // 16777216 f
    float* xA     = pre + (size_t)B * S * NG;           //  4194304 f
    float* xB     = xA + (size_t)B * S * DM;            //  4194304 f

    hipMemsetAsync(merged, 0, (size_t)B * S * DIN * sizeof(float), stream);
    pool_kernel<<<dim3(B, 6), 128, 0, stream>>>(emb, ids, merged);
    mask_kernel<<<(B * S) / 4, 256, 0, stream>>>(merged, mask_out);

    dim3 ggrid(512, 8);

    // layer 1: 768 -> 128
    gemm_nt_bias<<<ggrid, 256, 0, stream>>>(merged, DIN, Wih1, b1, pre);
    lstm_rec<<<2 * B, 256, 0, stream>>>(pre, Whh1, nullptr, xA, 0);

    // layer 2: no residual
    gemm_nt_bias<<<ggrid, 256, 0, stream>>>(xA, DM, Wih, bb, pre);
    lstm_rec<<<2 * B, 256, 0, stream>>>(pre, Whh, nullptr, xB, 0);

    // layers 3..8: residual
    float* cur = xB;
    float* oth = xA;
    for (int l = 1; l < 7; ++l) {
        gemm_nt_bias<<<ggrid, 256, 0, stream>>>(cur, DM, Wih + (size_t)l * NG * DM,
                                                bb + (size_t)l * NG, pre);
        lstm_rec<<<2 * B, 256, 0, stream>>>(pre, Whh + (size_t)l * NG * H,
                                            cur, oth, 1);
        float* tmp = cur; cur = oth; oth = tmp;
    }
    // cur == xB after 6 swaps

    assemble_kernel<<<(B * S * 129 + 255) / 256, 256, 0, stream>>>(cur, wl, out0);
}

// Round 5
// 4379.949 us; speedup vs baseline: 1.0051x; 1.0051x over previous
//
#include <hip/hip_runtime.h>
#include <math.h>

#define B 64
#define S 512
#define DIN 768
#define H 64
#define G4 256   // 4*H gates per direction
#define NG 512   // 2 directions * 4H
#define DM 128   // bidirectional output width

__device__ __forceinline__ float sigm(float x) {
    return 1.0f / (1.0f + __expf(-x));
}
__device__ __forceinline__ float tanh_fast(float x) {
    // tanh(x) = 1 - 2/(exp(2x)+1); exact at +-inf, ~1e-7 rel err
    return 1.0f - 2.0f / (__expf(2.0f * x) + 1.0f);
}

// Raw workgroup barrier that drains ONLY LDS (lgkmcnt), leaving global
// prefetch loads in flight.
__device__ __forceinline__ void lds_barrier() {
    __builtin_amdgcn_sched_barrier(0);
    asm volatile("s_waitcnt lgkmcnt(0)" ::: "memory");
    __builtin_amdgcn_s_barrier();
    __builtin_amdgcn_sched_barrier(0);
}

// ---------------------------------------------------------------------------
// Pooling: word_ids are sorted per row -> run-length accumulate, no atomics.
// ---------------------------------------------------------------------------
__global__ void pool_kernel(const float* __restrict__ emb,
                            const int* __restrict__ ids,
                            float* __restrict__ merged) {
    int b = blockIdx.x;
    int d = blockIdx.y * 128 + threadIdx.x;
    __shared__ int ids_s[S];
    for (int i = threadIdx.x; i < S; i += blockDim.x) ids_s[i] = ids[b * S + i];
    __syncthreads();
    const float* eb = emb + (size_t)b * S * DIN + d;
    float* mb = merged + (size_t)b * S * DIN + d;
    float acc = 0.f;
    for (int s = 0; s < S; ++s) {
        acc += eb[(size_t)s * DIN];
        int id = ids_s[s];
        bool flush = (s == S - 1) || (ids_s[s + 1] != id);
        if (flush) {
            mb[(size_t)id * DIN] = acc;
            acc = 0.f;
        }
    }
}

// ---------------------------------------------------------------------------
// Mask: one 64-lane wave per (b,word) row; mask = (sum over 768 != 0)
// ---------------------------------------------------------------------------
__global__ void mask_kernel(const float* __restrict__ merged,
                            float* __restrict__ mask) {
    int row = blockIdx.x * 4 + (threadIdx.x >> 6);
    int lane = threadIdx.x & 63;
    const float* r = merged + (size_t)row * DIN;
    float s = 0.f;
    #pragma unroll
    for (int i = 0; i < DIN / 64; ++i) s += r[lane + i * 64];
    #pragma unroll
    for (int off = 32; off > 0; off >>= 1) s += __shfl_down(s, off);
    if (lane == 0) mask[row] = (s != 0.f) ? 1.0f : 0.0f;
}

// ---------------------------------------------------------------------------
// GEMM: C[m][n] = sum_k A[m][k] * Wt[n][k] + bias[n]
// ---------------------------------------------------------------------------
#define OUTER4(a, w)                                                       \
    acc[0][0] = fmaf(a.x, w.x, acc[0][0]);                                 \
    acc[0][1] = fmaf(a.x, w.y, acc[0][1]);                                 \
    acc[0][2] = fmaf(a.x, w.z, acc[0][2]);                                 \
    acc[0][3] = fmaf(a.x, w.w, acc[0][3]);                                 \
    acc[1][0] = fmaf(a.y, w.x, acc[1][0]);                                 \
    acc[1][1] = fmaf(a.y, w.y, acc[1][1]);                                 \
    acc[1][2] = fmaf(a.y, w.z, acc[1][2]);                                 \
    acc[1][3] = fmaf(a.y, w.w, acc[1][3]);                                 \
    acc[2][0] = fmaf(a.z, w.x, acc[2][0]);                                 \
    acc[2][1] = fmaf(a.z, w.y, acc[2][1]);                                 \
    acc[2][2] = fmaf(a.z, w.z, acc[2][2]);                                 \
    acc[2][3] = fmaf(a.z, w.w, acc[2][3]);                                 \
    acc[3][0] = fmaf(a.w, w.x, acc[3][0]);                                 \
    acc[3][1] = fmaf(a.w, w.y, acc[3][1]);                                 \
    acc[3][2] = fmaf(a.w, w.z, acc[3][2]);                                 \
    acc[3][3] = fmaf(a.w, w.w, acc[3][3]);

__global__ __launch_bounds__(256, 2) void gemm_nt_bias(
    const float* __restrict__ A, int K,
    const float* __restrict__ Wt, const float* __restrict__ bias,
    float* __restrict__ C) {
    __shared__ __align__(16) float As[16][68];
    __shared__ __align__(16) float Bs[16][68];
    int tid = threadIdx.x;
    int m0 = blockIdx.x * 64;
    int n0 = blockIdx.y * 64;
    int lr = tid >> 2;          // 0..63 tile row
    int lk = (tid & 3) << 2;    // k offset (float4)
    int tx = tid & 15, ty = tid >> 4;
    float acc[4][4] = {};
    const float* Ap = A + (size_t)(m0 + lr) * K + lk;
    const float* Wp = Wt + (size_t)(n0 + lr) * K + lk;

    float4 av = *(const float4*)(Ap);
    float4 wv = *(const float4*)(Wp);
    for (int k0 = 0; k0 < K; k0 += 16) {
        As[lk + 0][lr] = av.x; As[lk + 1][lr] = av.y;
        As[lk + 2][lr] = av.z; As[lk + 3][lr] = av.w;
        Bs[lk + 0][lr] = wv.x; Bs[lk + 1][lr] = wv.y;
        Bs[lk + 2][lr] = wv.z; Bs[lk + 3][lr] = wv.w;
        __syncthreads();
        float4 av2 = av, wv2 = wv;
        if (k0 + 16 < K) {
            av2 = *(const float4*)(Ap + k0 + 16);
            wv2 = *(const float4*)(Wp + k0 + 16);
        }
        #pragma unroll
        for (int k = 0; k < 16; ++k) {
            float4 a = *(const float4*)&As[k][ty << 2];
            float4 w = *(const float4*)&Bs[k][tx << 2];
            OUTER4(a, w);
        }
        __syncthreads();
        av = av2; wv = wv2;
    }
    float4 bv = *(const float4*)&bias[n0 + (tx << 2)];
    #pragma unroll
    for (int i = 0; i < 4; ++i) {
        float4 r;
        r.x = acc[i][0] + bv.x;
        r.y = acc[i][1] + bv.y;
        r.z = acc[i][2] + bv.z;
        r.w = acc[i][3] + bv.w;
        *(float4*)&C[(size_t)(m0 + (ty << 2) + i) * NG + n0 + (tx << 2)] = r;
    }
}

// ---------------------------------------------------------------------------
// Recurrence: 4 waves per (batch, direction) chain, K-SPLIT, lgkm-only
// barrier, and BATCHED h-broadcast: all 16 __shfl issued into registers
// before any consuming FMA, so the 16 ds_bpermute pipeline (~1 latency)
// instead of serializing (16 x ~120 cy = the R3/R4 step time).
// ---------------------------------------------------------------------------
__global__ __launch_bounds__(256, 1) void lstm_rec(
    const float* __restrict__ pre,   // [B*S][512]
    const float* __restrict__ Whh,   // [512][64] (dir*256+g rows)
    const float* __restrict__ xin,   // [B*S][128] or nullptr
    float* __restrict__ xout,        // [B*S][128]
    int residual) {
    int b = blockIdx.x >> 1;
    int dir = blockIdx.x & 1;
    int t = threadIdx.x;
    int w = t >> 6;     // wave id 0..3 -> k range [16w, 16w+16)
    int j = t & 63;     // hidden unit

    // weights: wgtG[kk] = W_hh[dir*256 + G*64 + j][16w + kk]
    float wgt0[16], wgt1[16], wgt2[16], wgt3[16];
    {
        const float* base = Whh + (size_t)(dir * G4 + j) * H + (w << 4);
        #pragma unroll
        for (int kk = 0; kk < 16; kk += 4) {
            float4 v;
            v = *(const float4*)(base + (size_t)0 * 64 * H + kk);
            wgt0[kk] = v.x; wgt0[kk+1] = v.y; wgt0[kk+2] = v.z; wgt0[kk+3] = v.w;
            v = *(const float4*)(base + (size_t)1 * 64 * H + kk);
            wgt1[kk] = v.x; wgt1[kk+1] = v.y; wgt1[kk+2] = v.z; wgt1[kk+3] = v.w;
            v = *(const float4*)(base + (size_t)2 * 64 * H + kk);
            wgt2[kk] = v.x; wgt2[kk+1] = v.y; wgt2[kk+2] = v.z; wgt2[kk+3] = v.w;
            v = *(const float4*)(base + (size_t)3 * 64 * H + kk);
            wgt3[kk] = v.x; wgt3[kk+1] = v.y; wgt3[kk+2] = v.z; wgt3[kk+3] = v.w;
        }
    }

    // pre stream: wave w, lane j reads pre[s][dir*256 + w*64 + j]
    const float* preb = pre + (size_t)b * S * NG + dir * G4 + (w << 6) + j;
    const float* xinb = xin + (size_t)b * S * DM + dir * H + j;   // wave0 only
    float* xoutb = xout + (size_t)b * S * DM + dir * H + j;       // wave0 only

    float pbuf[4], rb[4] = {0.f, 0.f, 0.f, 0.f};
    #pragma unroll
    for (int i = 0; i < 4; ++i) {
        int s = dir ? (S - 1 - i) : i;
        pbuf[i] = preb[(size_t)s * NG];
        if (residual && w == 0) rb[i] = xinb[(size_t)s * DM];
    }

    __shared__ __align__(16) float part[2][4][64][4];

    int kbase = w << 4;
    float h = 0.f, c = 0.f;
    #pragma unroll 4
    for (int step = 0; step < S; ++step) {
        int s = dir ? (S - 1 - step) : step;
        int q = step & 3;
        int pp = step & 1;
        float p = pbuf[q];
        float rv = rb[q];
        int sn = step + 4;
        if (sn < S) {
            int s2 = dir ? (S - 1 - sn) : sn;
            pbuf[q] = preb[(size_t)s2 * NG];
            if (residual && w == 0) rb[q] = xinb[(size_t)s2 * DM];
        }

        // ---- phase 1: batched broadcast (16 bpermutes, no consumers between)
        float hk[16];
        #pragma unroll
        for (int kk = 0; kk < 16; ++kk) hk[kk] = __shfl(h, kbase + kk);

        // ---- phase 2: FMAs
        float a0 = (w == 0) ? p : 0.f;
        float a1 = (w == 1) ? p : 0.f;
        float a2 = (w == 2) ? p : 0.f;
        float a3 = (w == 3) ? p : 0.f;
        #pragma unroll
        for (int kk = 0; kk < 16; ++kk) {
            a0 = fmaf(hk[kk], wgt0[kk], a0);
            a1 = fmaf(hk[kk], wgt1[kk], a1);
            a2 = fmaf(hk[kk], wgt2[kk], a2);
            a3 = fmaf(hk[kk], wgt3[kk], a3);
        }
        *(float4*)&part[pp][w][j][0] = make_float4(a0, a1, a2, a3);
        lds_barrier();
        float4 v0 = *(const float4*)&part[pp][0][j][0];
        float4 v1 = *(const float4*)&part[pp][1][j][0];
        float4 v2 = *(const float4*)&part[pp][2][j][0];
        float4 v3 = *(const float4*)&part[pp][3][j][0];
        float gi = (v0.x + v1.x) + (v2.x + v3.x);
        float gf = (v0.y + v1.y) + (v2.y + v3.y);
        float gg = (v0.z + v1.z) + (v2.z + v3.z);
        float go = (v0.w + v1.w) + (v2.w + v3.w);
        c = sigm(gf) * c + sigm(gi) * tanh_fast(gg);
        h = sigm(go) * tanh_fast(c);
        if (w == 0) xoutb[(size_t)s * DM] = h + rv;
    }
}

// ---------------------------------------------------------------------------
// Assemble: out0[b,s,0:128] = x, out0[b,s,128] = sn_word_len[b,s]
// ---------------------------------------------------------------------------
__global__ void assemble_kernel(const float* __restrict__ x,
                                const float* __restrict__ wl,
                                float* __restrict__ out0) {
    int idx = blockIdx.x * blockDim.x + threadIdx.x;
    if (idx >= B * S * 129) return;
    int c = idx % 129;
    int bs = idx / 129;
    out0[idx] = (c < 128) ? x[(size_t)bs * DM + c] : wl[bs];
}

extern "C" void kernel_launch(void* const* d_in, const int* in_sizes, int n_in,
                              void* d_out, int out_size, void* d_ws, size_t ws_size,
                              hipStream_t stream) {
    const float* emb  = (const float*)d_in[0];
    const float* wl   = (const float*)d_in[1];
    const float* Wih1 = (const float*)d_in[2];  // [512][768]
    const float* Whh1 = (const float*)d_in[3];  // [512][64]
    const float* b1   = (const float*)d_in[4];  // [512]
    const float* Wih  = (const float*)d_in[5];  // [7][512][128]
    const float* Whh  = (const float*)d_in[6];  // [7][512][64]
    const float* bb   = (const float*)d_in[7];  // [7][512]
    const int*   ids  = (const int*)d_in[8];

    float* out0 = (float*)d_out;
    float* mask_out = out0 + (size_t)B * S * 129;

    float* merged = (float*)d_ws;                       // 25165824 f
    float* pre    = merged + (size_t)B * S * DIN;       // 16777216 f
    float* xA     = pre + (size_t)B * S * NG;           //  4194304 f
    float* xB     = xA + (size_t)B * S * DM;            //  4194304 f

    hipMemsetAsync(merged, 0, (size_t)B * S * DIN * sizeof(float), stream);
    pool_kernel<<<dim3(B, 6), 128, 0, stream>>>(emb, ids, merged);
    mask_kernel<<<(B * S) / 4, 256, 0, stream>>>(merged, mask_out);

    dim3 ggrid(512, 8);

    // layer 1: 768 -> 128
    gemm_nt_bias<<<ggrid, 256, 0, stream>>>(merged, DIN, Wih1, b1, pre);
    lstm_rec<<<2 * B, 256, 0, stream>>>(pre, Whh1, nullptr, xA, 0);

    // layer 2: no residual
    gemm_nt_bias<<<ggrid, 256, 0, stream>>>(xA, DM, Wih, bb, pre);
    lstm_rec<<<2 * B, 256, 0, stream>>>(pre, Whh, nullptr, xB, 0);

    // layers 3..8: residual
    float* cur = xB;
    float* oth = xA;
    for (int l = 1; l < 7; ++l) {
        gemm_nt_bias<<<ggrid, 256, 0, stream>>>(cur, DM, Wih + (size_t)l * NG * DM,
                                                bb + (size_t)l * NG, pre);
        lstm_rec<<<2 * B, 256, 0, stream>>>(pre, Whh + (size_t)l * NG * H,
                                            cur, oth, 1);
        float* tmp = cur; cur = oth; oth = tmp;
    }
    // cur == xB after 6 swaps

    assemble_kernel<<<(B * S * 129 + 255) / 256, 256, 0, stream>>>(cur, wl, out0);
}

// Round 6
// 3065.770 us; speedup vs baseline: 1.4359x; 1.4287x over previous
//
#include <hip/hip_runtime.h>
#include <math.h>
#include <stdint.h>

#define B 64
#define S 512
#define DIN 768
#define H 64
#define G4 256   // 4*H gates per direction
#define NG 512   // 2 directions * 4H
#define DM 128   // bidirectional output width

typedef _Float16 h2_t __attribute__((ext_vector_type(2)));

#if defined(__has_builtin)
#if __has_builtin(__builtin_amdgcn_fdot2)
#define HAS_FDOT2 1
#endif
#endif

__device__ __forceinline__ h2_t u2h(uint32_t u) {
    h2_t h;
    __builtin_memcpy(&h, &u, 4);
    return h;
}

__device__ __forceinline__ float dot2f(h2_t a, h2_t b, float acc) {
#ifdef HAS_FDOT2
    return __builtin_amdgcn_fdot2(a, b, acc, false);
#else
    acc = fmaf((float)a.x, (float)b.x, acc);
    return fmaf((float)a.y, (float)b.y, acc);
#endif
}

__device__ __forceinline__ float sigm(float x) {
    return 1.0f / (1.0f + __expf(-x));
}
__device__ __forceinline__ float tanh_fast(float x) {
    // tanh(x) = 1 - 2/(exp(2x)+1); exact at +-inf, ~1e-7 rel err
    return 1.0f - 2.0f / (__expf(2.0f * x) + 1.0f);
}

// ---------------------------------------------------------------------------
// Pooling: word_ids are sorted per row -> run-length accumulate, no atomics.
// ---------------------------------------------------------------------------
__global__ void pool_kernel(const float* __restrict__ emb,
                            const int* __restrict__ ids,
                            float* __restrict__ merged) {
    int b = blockIdx.x;
    int d = blockIdx.y * 128 + threadIdx.x;
    __shared__ int ids_s[S];
    for (int i = threadIdx.x; i < S; i += blockDim.x) ids_s[i] = ids[b * S + i];
    __syncthreads();
    const float* eb = emb + (size_t)b * S * DIN + d;
    float* mb = merged + (size_t)b * S * DIN + d;
    float acc = 0.f;
    for (int s = 0; s < S; ++s) {
        acc += eb[(size_t)s * DIN];
        int id = ids_s[s];
        bool flush = (s == S - 1) || (ids_s[s + 1] != id);
        if (flush) {
            mb[(size_t)id * DIN] = acc;
            acc = 0.f;
        }
    }
}

// ---------------------------------------------------------------------------
// Mask: one 64-lane wave per (b,word) row; mask = (sum over 768 != 0)
// ---------------------------------------------------------------------------
__global__ void mask_kernel(const float* __restrict__ merged,
                            float* __restrict__ mask) {
    int row = blockIdx.x * 4 + (threadIdx.x >> 6);
    int lane = threadIdx.x & 63;
    const float* r = merged + (size_t)row * DIN;
    float s = 0.f;
    #pragma unroll
    for (int i = 0; i < DIN / 64; ++i) s += r[lane + i * 64];
    #pragma unroll
    for (int off = 32; off > 0; off >>= 1) s += __shfl_down(s, off);
    if (lane == 0) mask[row] = (s != 0.f) ? 1.0f : 0.0f;
}

// ---------------------------------------------------------------------------
// GEMM: C[m][n] = sum_k A[m][k] * Wt[n][k] + bias[n]
// ---------------------------------------------------------------------------
#define OUTER4(a, w)                                                       \
    acc[0][0] = fmaf(a.x, w.x, acc[0][0]);                                 \
    acc[0][1] = fmaf(a.x, w.y, acc[0][1]);                                 \
    acc[0][2] = fmaf(a.x, w.z, acc[0][2]);                                 \
    acc[0][3] = fmaf(a.x, w.w, acc[0][3]);                                 \
    acc[1][0] = fmaf(a.y, w.x, acc[1][0]);                                 \
    acc[1][1] = fmaf(a.y, w.y, acc[1][1]);                                 \
    acc[1][2] = fmaf(a.y, w.z, acc[1][2]);                                 \
    acc[1][3] = fmaf(a.y, w.w, acc[1][3]);                                 \
    acc[2][0] = fmaf(a.z, w.x, acc[2][0]);                                 \
    acc[2][1] = fmaf(a.z, w.y, acc[2][1]);                                 \
    acc[2][2] = fmaf(a.z, w.z, acc[2][2]);                                 \
    acc[2][3] = fmaf(a.z, w.w, acc[2][3]);                                 \
    acc[3][0] = fmaf(a.w, w.x, acc[3][0]);                                 \
    acc[3][1] = fmaf(a.w, w.y, acc[3][1]);                                 \
    acc[3][2] = fmaf(a.w, w.z, acc[3][2]);                                 \
    acc[3][3] = fmaf(a.w, w.w, acc[3][3]);

__global__ __launch_bounds__(256, 2) void gemm_nt_bias(
    const float* __restrict__ A, int K,
    const float* __restrict__ Wt, const float* __restrict__ bias,
    float* __restrict__ C) {
    __shared__ __align__(16) float As[16][68];
    __shared__ __align__(16) float Bs[16][68];
    int tid = threadIdx.x;
    int m0 = blockIdx.x * 64;
    int n0 = blockIdx.y * 64;
    int lr = tid >> 2;          // 0..63 tile row
    int lk = (tid & 3) << 2;    // k offset (float4)
    int tx = tid & 15, ty = tid >> 4;
    float acc[4][4] = {};
    const float* Ap = A + (size_t)(m0 + lr) * K + lk;
    const float* Wp = Wt + (size_t)(n0 + lr) * K + lk;

    float4 av = *(const float4*)(Ap);
    float4 wv = *(const float4*)(Wp);
    for (int k0 = 0; k0 < K; k0 += 16) {
        As[lk + 0][lr] = av.x; As[lk + 1][lr] = av.y;
        As[lk + 2][lr] = av.z; As[lk + 3][lr] = av.w;
        Bs[lk + 0][lr] = wv.x; Bs[lk + 1][lr] = wv.y;
        Bs[lk + 2][lr] = wv.z; Bs[lk + 3][lr] = wv.w;
        __syncthreads();
        float4 av2 = av, wv2 = wv;
        if (k0 + 16 < K) {
            av2 = *(const float4*)(Ap + k0 + 16);
            wv2 = *(const float4*)(Wp + k0 + 16);
        }
        #pragma unroll
        for (int k = 0; k < 16; ++k) {
            float4 a = *(const float4*)&As[k][ty << 2];
            float4 w = *(const float4*)&Bs[k][tx << 2];
            OUTER4(a, w);
        }
        __syncthreads();
        av = av2; wv = wv2;
    }
    float4 bv = *(const float4*)&bias[n0 + (tx << 2)];
    #pragma unroll
    for (int i = 0; i < 4; ++i) {
        float4 r;
        r.x = acc[i][0] + bv.x;
        r.y = acc[i][1] + bv.y;
        r.z = acc[i][2] + bv.z;
        r.w = acc[i][3] + bv.w;
        *(float4*)&C[(size_t)(m0 + (ty << 2) + i) * NG + n0 + (tx << 2)] = r;
    }
}

// ---------------------------------------------------------------------------
// Recurrence: ONE WAVE per (batch, direction) chain. Zero barriers.
// Lane j owns hidden unit j: all 4 gate rows as f16-packed half2 weights
// (128 VGPRs, no spill). h exchanged through a 128-byte LDS buffer:
// ds_write_b16 own h, then 8 broadcast ds_read_b128 (same-wave DS ordering,
// lgkmcnt only, no barrier). Recurrent dot via v_dot2_f32_f16 (f32 acc).
// pre-activations (fp32, from GEMM) prefetched 4 steps deep.
// ---------------------------------------------------------------------------
__global__ __launch_bounds__(64, 1) void lstm_rec(
    const float* __restrict__ pre,   // [B*S][512]
    const float* __restrict__ Whh,   // [512][64] (dir*256+g rows)
    const float* __restrict__ xin,   // [B*S][128] or nullptr
    float* __restrict__ xout,        // [B*S][128]
    int residual) {
    int b = blockIdx.x >> 1;
    int dir = blockIdx.x & 1;
    int j = threadIdx.x & 63;

    // Pack weights: wg[g][kk] = (W[g*64+j][2kk], W[g*64+j][2kk+1]) as half2
    h2_t wg0[32], wg1[32], wg2[32], wg3[32];
    {
        const float* w0 = Whh + (size_t)(dir * G4 + 0 * H + j) * H;
        const float* w1 = Whh + (size_t)(dir * G4 + 1 * H + j) * H;
        const float* w2 = Whh + (size_t)(dir * G4 + 2 * H + j) * H;
        const float* w3 = Whh + (size_t)(dir * G4 + 3 * H + j) * H;
        #pragma unroll
        for (int kk = 0; kk < 32; ++kk) {
            float2 v;
            h2_t p;
            v = *(const float2*)&w0[kk * 2];
            p.x = (_Float16)v.x; p.y = (_Float16)v.y; wg0[kk] = p;
            v = *(const float2*)&w1[kk * 2];
            p.x = (_Float16)v.x; p.y = (_Float16)v.y; wg1[kk] = p;
            v = *(const float2*)&w2[kk * 2];
            p.x = (_Float16)v.x; p.y = (_Float16)v.y; wg2[kk] = p;
            v = *(const float2*)&w3[kk * 2];
            p.x = (_Float16)v.x; p.y = (_Float16)v.y; wg3[kk] = p;
        }
    }

    const float* preb = pre + (size_t)b * S * NG + dir * G4 + j;
    const float* xinb = xin + (size_t)b * S * DM + dir * H + j;
    float* xoutb = xout + (size_t)b * S * DM + dir * H + j;

    float pi[4], pf[4], pg_[4], po[4], rb[4] = {0.f, 0.f, 0.f, 0.f};
    #pragma unroll
    for (int i = 0; i < 4; ++i) {
        int s = dir ? (S - 1 - i) : i;
        const float* p = preb + (size_t)s * NG;
        pi[i] = p[0];
        pf[i] = p[64];
        pg_[i] = p[128];
        po[i] = p[192];
        if (residual) rb[i] = xinb[(size_t)s * DM];
    }

    __shared__ __align__(16) _Float16 shh[64];
    shh[j] = (_Float16)0.f;

    float c = 0.f;
    #pragma unroll 4
    for (int step = 0; step < S; ++step) {
        int s = dir ? (S - 1 - step) : step;
        int q = step & 3;
        float ai = pi[q], af = pf[q], ag = pg_[q], ao = po[q];
        float rv = rb[q];
        int sn = step + 4;
        if (sn < S) {
            int s2 = dir ? (S - 1 - sn) : sn;
            const float* p = preb + (size_t)s2 * NG;
            pi[q] = p[0];
            pf[q] = p[64];
            pg_[q] = p[128];
            po[q] = p[192];
            if (residual) rb[q] = xinb[(size_t)s2 * DM];
        }

        // Broadcast-read all 64 h values (8 x ds_read_b128, uniform addr)
        uint4 hq[8];
        const uint4* hp = (const uint4*)shh;
        #pragma unroll
        for (int r = 0; r < 8; ++r) hq[r] = hp[r];

        #pragma unroll
        for (int r = 0; r < 8; ++r) {
            uint32_t uu[4] = {hq[r].x, hq[r].y, hq[r].z, hq[r].w};
            #pragma unroll
            for (int cc = 0; cc < 4; ++cc) {
                int kk = r * 4 + cc;
                h2_t hh = u2h(uu[cc]);
                ai = dot2f(hh, wg0[kk], ai);
                af = dot2f(hh, wg1[kk], af);
                ag = dot2f(hh, wg2[kk], ag);
                ao = dot2f(hh, wg3[kk], ao);
            }
        }
        c = sigm(af) * c + sigm(ai) * tanh_fast(ag);
        float h = sigm(ao) * tanh_fast(c);
        shh[j] = (_Float16)h;
        xoutb[(size_t)s * DM] = h + rv;
    }
}

// ---------------------------------------------------------------------------
// Assemble: out0[b,s,0:128] = x, out0[b,s,128] = sn_word_len[b,s]
// ---------------------------------------------------------------------------
__global__ void assemble_kernel(const float* __restrict__ x,
                                const float* __restrict__ wl,
                                float* __restrict__ out0) {
    int idx = blockIdx.x * blockDim.x + threadIdx.x;
    if (idx >= B * S * 129) return;
    int c = idx % 129;
    int bs = idx / 129;
    out0[idx] = (c < 128) ? x[(size_t)bs * DM + c] : wl[bs];
}

extern "C" void kernel_launch(void* const* d_in, const int* in_sizes, int n_in,
                              void* d_out, int out_size, void* d_ws, size_t ws_size,
                              hipStream_t stream) {
    const float* emb  = (const float*)d_in[0];
    const float* wl   = (const float*)d_in[1];
    const float* Wih1 = (const float*)d_in[2];  // [512][768]
    const float* Whh1 = (const float*)d_in[3];  // [512][64]
    const float* b1   = (const float*)d_in[4];  // [512]
    const float* Wih  = (const float*)d_in[5];  // [7][512][128]
    const float* Whh  = (const float*)d_in[6];  // [7][512][64]
    const float* bb   = (const float*)d_in[7];  // [7][512]
    const int*   ids  = (const int*)d_in[8];

    float* out0 = (float*)d_out;
    float* mask_out = out0 + (size_t)B * S * 129;

    float* merged = (float*)d_ws;                       // 25165824 f
    float* pre    = merged + (size_t)B * S * DIN;       // 16777216 f
    float* xA     = pre + (size_t)B * S * NG;           //  4194304 f
    float* xB     = xA + (size_t)B * S * DM;            //  4194304 f

    hipMemsetAsync(merged, 0, (size_t)B * S * DIN * sizeof(float), stream);
    pool_kernel<<<dim3(B, 6), 128, 0, stream>>>(emb, ids, merged);
    mask_kernel<<<(B * S) / 4, 256, 0, stream>>>(merged, mask_out);

    dim3 ggrid(512, 8);

    // layer 1: 768 -> 128
    gemm_nt_bias<<<ggrid, 256, 0, stream>>>(merged, DIN, Wih1, b1, pre);
    lstm_rec<<<2 * B, 64, 0, stream>>>(pre, Whh1, nullptr, xA, 0);

    // layer 2: no residual
    gemm_nt_bias<<<ggrid, 256, 0, stream>>>(xA, DM, Wih, bb, pre);
    lstm_rec<<<2 * B, 64, 0, stream>>>(pre, Whh, nullptr, xB, 0);

    // layers 3..8: residual
    float* cur = xB;
    float* oth = xA;
    for (int l = 1; l < 7; ++l) {
        gemm_nt_bias<<<ggrid, 256, 0, stream>>>(cur, DM, Wih + (size_t)l * NG * DM,
                                                bb + (size_t)l * NG, pre);
        lstm_rec<<<2 * B, 64, 0, stream>>>(pre, Whh + (size_t)l * NG * H,
                                           cur, oth, 1);
        float* tmp = cur; cur = oth; oth = tmp;
    }
    // cur == xB after 6 swaps

    assemble_kernel<<<(B * S * 129 + 255) / 256, 256, 0, stream>>>(cur, wl, out0);
}

// Round 7
// 2684.791 us; speedup vs baseline: 1.6397x; 1.1419x over previous
//
#include <hip/hip_runtime.h>
#include <math.h>
#include <stdint.h>

#define B 64
#define S 512
#define DIN 768
#define H 64
#define G4 256   // 4*H gates per direction
#define NG 512   // 2 directions * 4H
#define DM 128   // bidirectional output width

typedef _Float16 h2_t __attribute__((ext_vector_type(2)));
typedef _Float16 f16x8 __attribute__((ext_vector_type(8)));
typedef float f32x4 __attribute__((ext_vector_type(4)));

#if defined(__has_builtin)
#if __has_builtin(__builtin_amdgcn_fdot2)
#define HAS_FDOT2 1
#endif
#endif

__device__ __forceinline__ h2_t u2h(uint32_t u) {
    h2_t h;
    __builtin_memcpy(&h, &u, 4);
    return h;
}

__device__ __forceinline__ float dot2f(h2_t a, h2_t b, float acc) {
#ifdef HAS_FDOT2
    return __builtin_amdgcn_fdot2(a, b, acc, false);
#else
    acc = fmaf((float)a.x, (float)b.x, acc);
    return fmaf((float)a.y, (float)b.y, acc);
#endif
}

__device__ __forceinline__ float sigm(float x) {
    return 1.0f / (1.0f + __expf(-x));
}
__device__ __forceinline__ float tanh_fast(float x) {
    return 1.0f - 2.0f / (__expf(2.0f * x) + 1.0f);
}

// ---------------------------------------------------------------------------
// Pooling: word_ids are sorted per row -> run-length accumulate, no atomics.
// ---------------------------------------------------------------------------
__global__ void pool_kernel(const float* __restrict__ emb,
                            const int* __restrict__ ids,
                            float* __restrict__ merged) {
    int b = blockIdx.x;
    int d = blockIdx.y * 128 + threadIdx.x;
    __shared__ int ids_s[S];
    for (int i = threadIdx.x; i < S; i += blockDim.x) ids_s[i] = ids[b * S + i];
    __syncthreads();
    const float* eb = emb + (size_t)b * S * DIN + d;
    float* mb = merged + (size_t)b * S * DIN + d;
    float acc = 0.f;
    for (int s = 0; s < S; ++s) {
        acc += eb[(size_t)s * DIN];
        int id = ids_s[s];
        bool flush = (s == S - 1) || (ids_s[s + 1] != id);
        if (flush) {
            mb[(size_t)id * DIN] = acc;
            acc = 0.f;
        }
    }
}

// ---------------------------------------------------------------------------
// Mask: one 64-lane wave per (b,word) row; mask = (sum over 768 != 0)
// ---------------------------------------------------------------------------
__global__ void mask_kernel(const float* __restrict__ merged,
                            float* __restrict__ mask) {
    int row = blockIdx.x * 4 + (threadIdx.x >> 6);
    int lane = threadIdx.x & 63;
    const float* r = merged + (size_t)row * DIN;
    float s = 0.f;
    #pragma unroll
    for (int i = 0; i < DIN / 64; ++i) s += r[lane + i * 64];
    #pragma unroll
    for (int off = 32; off > 0; off >>= 1) s += __shfl_down(s, off);
    if (lane == 0) mask[row] = (s != 0.f) ? 1.0f : 0.0f;
}

// ---------------------------------------------------------------------------
// MFMA GEMM: C[m][n] = sum_k A[m][k]*Wt[n][k] + bias[n], via f16 MFMA.
// A,Wt f32 in global; converted to f16 while staging into LDS.
// Block tile 128x64, BK=32, 256 threads = 4 waves in 2x2 quadrants,
// each wave 64x32 = 4x2 fragments of 16x16x32. LDS rows padded to 40 f16
// (80 B) so frag reads spread across banks. Grid: (N/64, M/128), N fastest
// so the 8 blocks sharing an A-panel run concurrently (L2/L3 locality).
// ---------------------------------------------------------------------------
#define LDK 40

__global__ __launch_bounds__(256, 2) void gemm_mfma(
    const float* __restrict__ A, int K,
    const float* __restrict__ Wt, const float* __restrict__ bias,
    float* __restrict__ C) {
    __shared__ __align__(16) _Float16 Alds[128][LDK];
    __shared__ __align__(16) _Float16 Blds[64][LDK];
    int tid = threadIdx.x;
    int lane = tid & 63;
    int wave = tid >> 6;
    int wm = wave >> 1, wn = wave & 1;
    int n0 = blockIdx.x * 64;
    int m0 = blockIdx.y * 128;

    int tr = tid >> 2;            // staging row 0..63
    int tc = (tid & 3) << 3;      // staging k-chunk (8 floats)

    f32x4 acc[4][2] = {};

    const float* Ab = A + (size_t)m0 * K;
    for (int k0 = 0; k0 < K; k0 += 32) {
        // stage A rows tr, tr+64 (f32 -> f16)
        {
            const float* src = Ab + (size_t)tr * K + k0 + tc;
            float4 v0 = *(const float4*)(src);
            float4 v1 = *(const float4*)(src + 4);
            _Float16* dst = &Alds[tr][tc];
            dst[0] = (_Float16)v0.x; dst[1] = (_Float16)v0.y;
            dst[2] = (_Float16)v0.z; dst[3] = (_Float16)v0.w;
            dst[4] = (_Float16)v1.x; dst[5] = (_Float16)v1.y;
            dst[6] = (_Float16)v1.z; dst[7] = (_Float16)v1.w;
            src += (size_t)64 * K;
            float4 v2 = *(const float4*)(src);
            float4 v3 = *(const float4*)(src + 4);
            dst = &Alds[tr + 64][tc];
            dst[0] = (_Float16)v2.x; dst[1] = (_Float16)v2.y;
            dst[2] = (_Float16)v2.z; dst[3] = (_Float16)v2.w;
            dst[4] = (_Float16)v3.x; dst[5] = (_Float16)v3.y;
            dst[6] = (_Float16)v3.z; dst[7] = (_Float16)v3.w;
        }
        // stage B rows 0..63 (f32 -> f16)
        {
            const float* src = Wt + (size_t)(n0 + tr) * K + k0 + tc;
            float4 v0 = *(const float4*)(src);
            float4 v1 = *(const float4*)(src + 4);
            _Float16* dst = &Blds[tr][tc];
            dst[0] = (_Float16)v0.x; dst[1] = (_Float16)v0.y;
            dst[2] = (_Float16)v0.z; dst[3] = (_Float16)v0.w;
            dst[4] = (_Float16)v1.x; dst[5] = (_Float16)v1.y;
            dst[6] = (_Float16)v1.z; dst[7] = (_Float16)v1.w;
        }
        __syncthreads();

        int fr = lane & 15;          // frag row/col within 16
        int kg = (lane >> 4) << 3;   // contiguous k-offset
        f16x8 af[4], bf[2];
        #pragma unroll
        for (int mf = 0; mf < 4; ++mf)
            af[mf] = *(const f16x8*)&Alds[wm * 64 + mf * 16 + fr][kg];
        #pragma unroll
        for (int nf = 0; nf < 2; ++nf)
            bf[nf] = *(const f16x8*)&Blds[wn * 32 + nf * 16 + fr][kg];
        #pragma unroll
        for (int mf = 0; mf < 4; ++mf)
            #pragma unroll
            for (int nf = 0; nf < 2; ++nf)
                acc[mf][nf] = __builtin_amdgcn_mfma_f32_16x16x32_f16(
                    af[mf], bf[nf], acc[mf][nf], 0, 0, 0);
        __syncthreads();
    }

    // epilogue: C row = (lane>>4)*4 + reg, col = lane&15  (m89-verified)
    int col = lane & 15;
    int r4 = (lane >> 4) << 2;
    #pragma unroll
    for (int nf = 0; nf < 2; ++nf) {
        int n = n0 + wn * 32 + nf * 16 + col;
        float bv = bias[n];
        #pragma unroll
        for (int mf = 0; mf < 4; ++mf) {
            #pragma unroll
            for (int reg = 0; reg < 4; ++reg) {
                int m = m0 + wm * 64 + mf * 16 + r4 + reg;
                C[(size_t)m * NG + n] = acc[mf][nf][reg] + bv;
            }
        }
    }
}

// ---------------------------------------------------------------------------
// Recurrence: ONE WAVE per (batch, direction) chain. Zero barriers.
// f16-packed W_hh in 128 VGPRs, fdot2 accumulate in f32, h through a
// 128-byte LDS buffer (same-wave DS ordering, no barrier).
// ---------------------------------------------------------------------------
__global__ __launch_bounds__(64, 1) void lstm_rec(
    const float* __restrict__ pre,   // [B*S][512]
    const float* __restrict__ Whh,   // [512][64] (dir*256+g rows)
    const float* __restrict__ xin,   // [B*S][128] or nullptr
    float* __restrict__ xout,        // [B*S][128]
    int residual) {
    int b = blockIdx.x >> 1;
    int dir = blockIdx.x & 1;
    int j = threadIdx.x & 63;

    h2_t wg0[32], wg1[32], wg2[32], wg3[32];
    {
        const float* w0 = Whh + (size_t)(dir * G4 + 0 * H + j) * H;
        const float* w1 = Whh + (size_t)(dir * G4 + 1 * H + j) * H;
        const float* w2 = Whh + (size_t)(dir * G4 + 2 * H + j) * H;
        const float* w3 = Whh + (size_t)(dir * G4 + 3 * H + j) * H;
        #pragma unroll
        for (int kk = 0; kk < 32; ++kk) {
            float2 v;
            h2_t p;
            v = *(const float2*)&w0[kk * 2];
            p.x = (_Float16)v.x; p.y = (_Float16)v.y; wg0[kk] = p;
            v = *(const float2*)&w1[kk * 2];
            p.x = (_Float16)v.x; p.y = (_Float16)v.y; wg1[kk] = p;
            v = *(const float2*)&w2[kk * 2];
            p.x = (_Float16)v.x; p.y = (_Float16)v.y; wg2[kk] = p;
            v = *(const float2*)&w3[kk * 2];
            p.x = (_Float16)v.x; p.y = (_Float16)v.y; wg3[kk] = p;
        }
    }

    const float* preb = pre + (size_t)b * S * NG + dir * G4 + j;
    const float* xinb = xin + (size_t)b * S * DM + dir * H + j;
    float* xoutb = xout + (size_t)b * S * DM + dir * H + j;

    float pi[4], pf[4], pg_[4], po[4], rb[4] = {0.f, 0.f, 0.f, 0.f};
    #pragma unroll
    for (int i = 0; i < 4; ++i) {
        int s = dir ? (S - 1 - i) : i;
        const float* p = preb + (size_t)s * NG;
        pi[i] = p[0];
        pf[i] = p[64];
        pg_[i] = p[128];
        po[i] = p[192];
        if (residual) rb[i] = xinb[(size_t)s * DM];
    }

    __shared__ __align__(16) _Float16 shh[64];
    shh[j] = (_Float16)0.f;

    float c = 0.f;
    #pragma unroll 4
    for (int step = 0; step < S; ++step) {
        int s = dir ? (S - 1 - step) : step;
        int q = step & 3;
        float ai = pi[q], af = pf[q], ag = pg_[q], ao = po[q];
        float rv = rb[q];
        int sn = step + 4;
        if (sn < S) {
            int s2 = dir ? (S - 1 - sn) : sn;
            const float* p = preb + (size_t)s2 * NG;
            pi[q] = p[0];
            pf[q] = p[64];
            pg_[q] = p[128];
            po[q] = p[192];
            if (residual) rb[q] = xinb[(size_t)s2 * DM];
        }

        uint4 hq[8];
        const uint4* hp = (const uint4*)shh;
        #pragma unroll
        for (int r = 0; r < 8; ++r) hq[r] = hp[r];

        #pragma unroll
        for (int r = 0; r < 8; ++r) {
            uint32_t uu[4] = {hq[r].x, hq[r].y, hq[r].z, hq[r].w};
            #pragma unroll
            for (int cc = 0; cc < 4; ++cc) {
                int kk = r * 4 + cc;
                h2_t hh = u2h(uu[cc]);
                ai = dot2f(hh, wg0[kk], ai);
                af = dot2f(hh, wg1[kk], af);
                ag = dot2f(hh, wg2[kk], ag);
                ao = dot2f(hh, wg3[kk], ao);
            }
        }
        c = sigm(af) * c + sigm(ai) * tanh_fast(ag);
        float h = sigm(ao) * tanh_fast(c);
        shh[j] = (_Float16)h;
        xoutb[(size_t)s * DM] = h + rv;
    }
}

// ---------------------------------------------------------------------------
// Assemble: out0[b,s,0:128] = x, out0[b,s,128] = sn_word_len[b,s]
// ---------------------------------------------------------------------------
__global__ void assemble_kernel(const float* __restrict__ x,
                                const float* __restrict__ wl,
                                float* __restrict__ out0) {
    int idx = blockIdx.x * blockDim.x + threadIdx.x;
    if (idx >= B * S * 129) return;
    int c = idx % 129;
    int bs = idx / 129;
    out0[idx] = (c < 128) ? x[(size_t)bs * DM + c] : wl[bs];
}

extern "C" void kernel_launch(void* const* d_in, const int* in_sizes, int n_in,
                              void* d_out, int out_size, void* d_ws, size_t ws_size,
                              hipStream_t stream) {
    const float* emb  = (const float*)d_in[0];
    const float* wl   = (const float*)d_in[1];
    const float* Wih1 = (const float*)d_in[2];  // [512][768]
    const float* Whh1 = (const float*)d_in[3];  // [512][64]
    const float* b1   = (const float*)d_in[4];  // [512]
    const float* Wih  = (const float*)d_in[5];  // [7][512][128]
    const float* Whh  = (const float*)d_in[6];  // [7][512][64]
    const float* bb   = (const float*)d_in[7];  // [7][512]
    const int*   ids  = (const int*)d_in[8];

    float* out0 = (float*)d_out;
    float* mask_out = out0 + (size_t)B * S * 129;

    float* merged = (float*)d_ws;                       // 25165824 f
    float* pre    = merged + (size_t)B * S * DIN;       // 16777216 f
    float* xA     = pre + (size_t)B * S * NG;           //  4194304 f
    float* xB     = xA + (size_t)B * S * DM;            //  4194304 f

    hipMemsetAsync(merged, 0, (size_t)B * S * DIN * sizeof(float), stream);
    pool_kernel<<<dim3(B, 6), 128, 0, stream>>>(emb, ids, merged);
    mask_kernel<<<(B * S) / 4, 256, 0, stream>>>(merged, mask_out);

    dim3 ggrid(NG / 64, (B * S) / 128);   // (8, 256), N fastest

    // layer 1: 768 -> 128
    gemm_mfma<<<ggrid, 256, 0, stream>>>(merged, DIN, Wih1, b1, pre);
    lstm_rec<<<2 * B, 64, 0, stream>>>(pre, Whh1, nullptr, xA, 0);

    // layer 2: no residual
    gemm_mfma<<<ggrid, 256, 0, stream>>>(xA, DM, Wih, bb, pre);
    lstm_rec<<<2 * B, 64, 0, stream>>>(pre, Whh, nullptr, xB, 0);

    // layers 3..8: residual
    float* cur = xB;
    float* oth = xA;
    for (int l = 1; l < 7; ++l) {
        gemm_mfma<<<ggrid, 256, 0, stream>>>(cur, DM, Wih + (size_t)l * NG * DM,
                                             bb + (size_t)l * NG, pre);
        lstm_rec<<<2 * B, 64, 0, stream>>>(pre, Whh + (size_t)l * NG * H,
                                           cur, oth, 1);
        float* tmp = cur; cur = oth; oth = tmp;
    }
    // cur == xB after 6 swaps

    assemble_kernel<<<(B * S * 129 + 255) / 256, 256, 0, stream>>>(cur, wl, out0);
}